// Round 1
// baseline (66.691 us; speedup 1.0000x reference)
//
#include <hip/hip_runtime.h>
#include <math.h>

// Problem constants (from reference setup_inputs)
#define NIMG 16
#define NGT  256
#define NANC 3
#define NCLS 80
#define NCH  85

// Level geometry: H=W in {80,40,20}, strides {8,16,32}
// cells per level: 16*80*80*3 = 307200 ; 16*40*40*3 = 76800 ; 16*20*20*3 = 19200
#define CELLS0 307200
#define CELLS1 76800
#define CELLS2 19200
#define CELLS_TOTAL 403200

__device__ __forceinline__ float bce_logits(float x, float t) {
    return fmaxf(x, 0.f) - x * t + log1pf(expf(-fabsf(x)));
}

__device__ __forceinline__ float sigmoidf(float x) {
    return 1.f / (1.f + expf(-x));
}

// One thread per (level, gt, j-offset, anchor): 3*256*3*3 = 6912 threads, 27 blocks.
// 2304 candidates per level = 9 blocks per level -> each block is single-level.
__global__ __launch_bounds__(256) void match_kernel(
    const float* __restrict__ p0, const float* __restrict__ p1, const float* __restrict__ p2,
    const float* __restrict__ gt_boxes, const float* __restrict__ anchors,
    const int* __restrict__ gt_labels, const int* __restrict__ image_ids,
    float* __restrict__ gt_obj, float* __restrict__ acc)
{
    const int tid = blockIdx.x * 256 + threadIdx.x;    // 0..6911
    const int l  = tid / (NGT * 9);
    const int r  = tid % (NGT * 9);
    const int g  = r / 9;
    const int jj = (r % 9) / 3;
    const int a  = r % 3;

    const float strides_[3] = {8.f, 16.f, 32.f};
    const int   dims_[3]    = {80, 40, 20};
    const int   bases_[3]   = {0, CELLS0, CELLS0 + CELLS1};
    const float* preds[3]   = {p0, p1, p2};

    float box_c = 0.f, cls_c = 0.f, cnt_c = 0.f;

    {
        const float s  = strides_[l];
        const int   HW = dims_[l];

        const float bx1 = gt_boxes[g*4+0], by1 = gt_boxes[g*4+1];
        const float bx2 = gt_boxes[g*4+2], by2 = gt_boxes[g*4+3];
        const float cx = (bx1 + bx2) * 0.5f, cy = (by1 + by2) * 0.5f;
        const float gw = bx2 - bx1,          gh = by2 - by1;

        const float aw = anchors[(l*3 + a)*2 + 0];
        const float ah = anchors[(l*3 + a)*2 + 1];

        const float rw = gw / aw, rh = gh / ah;
        const float mr = fmaxf(fmaxf(rw, 1.f/rw), fmaxf(rh, 1.f/rh));
        const bool size_ok = mr < 4.0f;

        const float xs = cx / s, ys = cy / s;
        const float cfx = floorf(xs), cfy = floorf(ys);
        const float fx = xs - cfx, fy = ys - cfy;
        const float dx = (fx < 0.5f) ? -1.f : 1.f;
        const float dy = (fy < 0.5f) ? -1.f : 1.f;

        const float ccx = cfx + ((jj == 1) ? dx : 0.f);
        const float ccy = cfy + ((jj == 2) ? dy : 0.f);
        const bool valid = (ccx >= 0.f) && (ccx < (float)HW) &&
                           (ccy >= 0.f) && (ccy < (float)HW);

        if (size_ok && valid) {
            const int gx = min(max((int)ccx, 0), HW - 1);
            const int gy = min(max((int)ccy, 0), HW - 1);
            const int img = image_ids[g];
            const int cell = ((img*HW + gy)*HW + gx)*3 + a;   // cell index within level
            const float* pl = preds[l] + (long long)cell * NCH;

            const float t0 = pl[0], t1 = pl[1], t2 = pl[2], t3 = pl[3];
            const float px = 2.f * sigmoidf(t0) - 0.5f + (float)gx;
            const float py = 2.f * sigmoidf(t1) - 0.5f + (float)gy;
            const float sw = sigmoidf(t2), sh = sigmoidf(t3);
            const float pw = 4.f * sw * sw * (aw / s);
            const float ph = 4.f * sh * sh * (ah / s);

            const float gcx = cx / s, gcy = cy / s, gww = gw / s, ghh = gh / s;

            // GIoU (cxcywh)
            const float b1l = px - pw*0.5f, b1r = px + pw*0.5f;
            const float b1t = py - ph*0.5f, b1b = py + ph*0.5f;
            const float b2l = gcx - gww*0.5f, b2r = gcx + gww*0.5f;
            const float b2t = gcy - ghh*0.5f, b2b = gcy + ghh*0.5f;

            const float iw = fmaxf(fminf(b1r, b2r) - fmaxf(b1l, b2l), 0.f);
            const float ih = fmaxf(fminf(b1b, b2b) - fmaxf(b1t, b2t), 0.f);
            const float inter = iw * ih;
            const float a1 = pw * ph, a2 = gww * ghh;
            const float uni = a1 + a2 - inter;
            const float iou = inter / (uni + 1e-7f);
            const float ew = fmaxf(b1r, b2r) - fminf(b1l, b2l);
            const float eh = fmaxf(b1b, b2b) - fminf(b1t, b2t);
            const float enc = ew * eh;
            const float giou = iou - (enc - uni) / (enc + 1e-7f);

            box_c = 1.f - giou;
            cnt_c = 1.f;

            // class BCE over 80 logits
            const int label = gt_labels[g];
            float cs = 0.f;
            #pragma unroll 4
            for (int c = 0; c < NCLS; ++c) {
                const float x = pl[5 + c];
                const float t = (c == label) ? 1.f : 0.f;
                cs += bce_logits(x, t);
            }
            cls_c = cs;

            // scatter-max objectness target (all values >= 0 -> uint-bit max is valid)
            const float obj_val = fmaxf(giou, 0.f);
            if (obj_val > 0.f) {
                atomicMax((unsigned int*)(gt_obj + bases_[l] + cell),
                          __float_as_uint(obj_val));
            }
        }
    }

    // block reduction (block is single-level: l = blockIdx.x / 9)
    __shared__ float s0[256], s1[256], s2[256];
    const int t = threadIdx.x;
    s0[t] = box_c; s1[t] = cls_c; s2[t] = cnt_c;
    __syncthreads();
    for (int off = 128; off > 0; off >>= 1) {
        if (t < off) { s0[t] += s0[t+off]; s1[t] += s1[t+off]; s2[t] += s2[t+off]; }
        __syncthreads();
    }
    if (t == 0) {
        const int lv = blockIdx.x / 9;
        atomicAdd(&acc[0 + lv], s0[0]);   // box numerator
        atomicAdd(&acc[3 + lv], s1[0]);   // cls numerator
        atomicAdd(&acc[6 + lv], s2[0]);   // cnt
    }
}

// One thread per cell over all levels: 403200 = 1575 * 256 exactly.
// Per-level mean folded in as per-element weight -> single accumulator.
__global__ __launch_bounds__(256) void obj_kernel(
    const float* __restrict__ p0, const float* __restrict__ p1, const float* __restrict__ p2,
    const float* __restrict__ gt_obj, float* __restrict__ acc)
{
    const int idx = blockIdx.x * 256 + threadIdx.x;
    const float* p; int cell; float w;
    if (idx < CELLS0)                { p = p0; cell = idx;                    w = 1.f / (float)CELLS0; }
    else if (idx < CELLS0 + CELLS1)  { p = p1; cell = idx - CELLS0;          w = 1.f / (float)CELLS1; }
    else                             { p = p2; cell = idx - CELLS0 - CELLS1; w = 1.f / (float)CELLS2; }

    const float x = p[(long long)cell * NCH + 4];
    const float t = gt_obj[idx];
    float contrib = bce_logits(x, t) * w;

    __shared__ float red[256];
    red[threadIdx.x] = contrib;
    __syncthreads();
    for (int off = 128; off > 0; off >>= 1) {
        if (threadIdx.x < off) red[threadIdx.x] += red[threadIdx.x + off];
        __syncthreads();
    }
    if (threadIdx.x == 0) atomicAdd(&acc[9], red[0]);
}

__global__ void finalize_kernel(const float* __restrict__ acc, float* __restrict__ out)
{
    if (blockIdx.x == 0 && threadIdx.x == 0) {
        float lb = 0.f, lc = 0.f;
        for (int l = 0; l < 3; ++l) {
            const float cnt = fmaxf(acc[6 + l], 1.f);
            lb += acc[0 + l] / cnt;
            lc += acc[3 + l] / (cnt * (float)NCLS);
        }
        out[0] = 0.05f * lb;   // LOSS_W[0]
        out[1] = acc[9];       // LOSS_W[1] = 1.0
        out[2] = 0.5f  * lc;   // LOSS_W[2]
    }
}

extern "C" void kernel_launch(void* const* d_in, const int* in_sizes, int n_in,
                              void* d_out, int out_size, void* d_ws, size_t ws_size,
                              hipStream_t stream) {
    const float* p0       = (const float*)d_in[0];
    const float* p1       = (const float*)d_in[1];
    const float* p2       = (const float*)d_in[2];
    const float* gt_boxes = (const float*)d_in[3];
    const float* anchors  = (const float*)d_in[4];
    const int*   gt_labels= (const int*)d_in[5];
    const int*   image_ids= (const int*)d_in[6];
    float* out = (float*)d_out;

    float* ws     = (float*)d_ws;
    float* gt_obj = ws;                 // CELLS_TOTAL floats
    float* acc    = ws + CELLS_TOTAL;   // 16 floats: [0..2]=box, [3..5]=cls, [6..8]=cnt, [9]=obj

    hipMemsetAsync(d_ws, 0, (CELLS_TOTAL + 16) * sizeof(float), stream);

    match_kernel<<<27, 256, 0, stream>>>(p0, p1, p2, gt_boxes, anchors,
                                         gt_labels, image_ids, gt_obj, acc);
    obj_kernel<<<1575, 256, 0, stream>>>(p0, p1, p2, gt_obj, acc);
    finalize_kernel<<<1, 64, 0, stream>>>(acc, out);
}

// Round 2
// 66.220 us; speedup vs baseline: 1.0071x; 1.0071x over previous
//
#include <hip/hip_runtime.h>
#include <math.h>

// Problem constants (from reference setup_inputs)
#define NIMG 16
#define NGT  256
#define NANC 3
#define NCLS 80
#define NCH  85

// Level geometry: H=W in {80,40,20}, strides {8,16,32}
// cells per level: 16*80*80*3 = 307200 ; 16*40*40*3 = 76800 ; 16*20*20*3 = 19200
#define CELLS0 307200
#define CELLS1 76800
#define CELLS2 19200
#define CELLS_TOTAL 403200
#define WS_FLOATS (CELLS_TOTAL + 16)   // gt_obj + acc[16]

__device__ __forceinline__ float bce_logits(float x, float t) {
    return fmaxf(x, 0.f) - x * t + log1pf(expf(-fabsf(x)));
}

__device__ __forceinline__ float sigmoidf(float x) {
    return 1.f / (1.f + expf(-x));
}

// Zero the whole workspace (gt_obj + accumulators) with float4 stores.
// WS_FLOATS = 403216 floats = 100804 float4 exactly.
__global__ __launch_bounds__(256) void zero_ws_kernel(float4* __restrict__ ws4, int n4)
{
    const int i = blockIdx.x * 256 + threadIdx.x;
    if (i < n4) ws4[i] = make_float4(0.f, 0.f, 0.f, 0.f);
}

// One thread per (level, gt, j-offset, anchor): 3*256*3*3 = 6912 threads, 27 blocks.
// 2304 candidates per level = 9 blocks per level -> each block is single-level.
__global__ __launch_bounds__(256) void match_kernel(
    const float* __restrict__ p0, const float* __restrict__ p1, const float* __restrict__ p2,
    const float* __restrict__ gt_boxes, const float* __restrict__ anchors,
    const int* __restrict__ gt_labels, const int* __restrict__ image_ids,
    float* __restrict__ gt_obj, float* __restrict__ acc)
{
    const int tid = blockIdx.x * 256 + threadIdx.x;    // 0..6911
    const int l  = tid / (NGT * 9);
    const int r  = tid % (NGT * 9);
    const int g  = r / 9;
    const int jj = (r % 9) / 3;
    const int a  = r % 3;

    const float strides_[3] = {8.f, 16.f, 32.f};
    const int   dims_[3]    = {80, 40, 20};
    const int   bases_[3]   = {0, CELLS0, CELLS0 + CELLS1};
    const float* preds[3]   = {p0, p1, p2};

    float box_c = 0.f, cls_c = 0.f, cnt_c = 0.f;

    {
        const float s  = strides_[l];
        const int   HW = dims_[l];

        const float bx1 = gt_boxes[g*4+0], by1 = gt_boxes[g*4+1];
        const float bx2 = gt_boxes[g*4+2], by2 = gt_boxes[g*4+3];
        const float cx = (bx1 + bx2) * 0.5f, cy = (by1 + by2) * 0.5f;
        const float gw = bx2 - bx1,          gh = by2 - by1;

        const float aw = anchors[(l*3 + a)*2 + 0];
        const float ah = anchors[(l*3 + a)*2 + 1];

        const float rw = gw / aw, rh = gh / ah;
        const float mr = fmaxf(fmaxf(rw, 1.f/rw), fmaxf(rh, 1.f/rh));
        const bool size_ok = mr < 4.0f;

        const float xs = cx / s, ys = cy / s;
        const float cfx = floorf(xs), cfy = floorf(ys);
        const float fx = xs - cfx, fy = ys - cfy;
        const float dx = (fx < 0.5f) ? -1.f : 1.f;
        const float dy = (fy < 0.5f) ? -1.f : 1.f;

        const float ccx = cfx + ((jj == 1) ? dx : 0.f);
        const float ccy = cfy + ((jj == 2) ? dy : 0.f);
        const bool valid = (ccx >= 0.f) && (ccx < (float)HW) &&
                           (ccy >= 0.f) && (ccy < (float)HW);

        if (size_ok && valid) {
            const int gx = min(max((int)ccx, 0), HW - 1);
            const int gy = min(max((int)ccy, 0), HW - 1);
            const int img = image_ids[g];
            const int cell = ((img*HW + gy)*HW + gx)*3 + a;   // cell index within level
            const float* pl = preds[l] + (long long)cell * NCH;

            const float t0 = pl[0], t1 = pl[1], t2 = pl[2], t3 = pl[3];
            const float px = 2.f * sigmoidf(t0) - 0.5f + (float)gx;
            const float py = 2.f * sigmoidf(t1) - 0.5f + (float)gy;
            const float sw = sigmoidf(t2), sh = sigmoidf(t3);
            const float pw = 4.f * sw * sw * (aw / s);
            const float ph = 4.f * sh * sh * (ah / s);

            const float gcx = cx / s, gcy = cy / s, gww = gw / s, ghh = gh / s;

            // GIoU (cxcywh)
            const float b1l = px - pw*0.5f, b1r = px + pw*0.5f;
            const float b1t = py - ph*0.5f, b1b = py + ph*0.5f;
            const float b2l = gcx - gww*0.5f, b2r = gcx + gww*0.5f;
            const float b2t = gcy - ghh*0.5f, b2b = gcy + ghh*0.5f;

            const float iw = fmaxf(fminf(b1r, b2r) - fmaxf(b1l, b2l), 0.f);
            const float ih = fmaxf(fminf(b1b, b2b) - fmaxf(b1t, b2t), 0.f);
            const float inter = iw * ih;
            const float a1 = pw * ph, a2 = gww * ghh;
            const float uni = a1 + a2 - inter;
            const float iou = inter / (uni + 1e-7f);
            const float ew = fmaxf(b1r, b2r) - fminf(b1l, b2l);
            const float eh = fmaxf(b1b, b2b) - fminf(b1t, b2t);
            const float enc = ew * eh;
            const float giou = iou - (enc - uni) / (enc + 1e-7f);

            box_c = 1.f - giou;
            cnt_c = 1.f;

            // class BCE over 80 logits
            const int label = gt_labels[g];
            float cs = 0.f;
            #pragma unroll 4
            for (int c = 0; c < NCLS; ++c) {
                const float x = pl[5 + c];
                const float t = (c == label) ? 1.f : 0.f;
                cs += bce_logits(x, t);
            }
            cls_c = cs;

            // scatter-max objectness target (all values >= 0 -> uint-bit max is valid)
            const float obj_val = fmaxf(giou, 0.f);
            if (obj_val > 0.f) {
                atomicMax((unsigned int*)(gt_obj + bases_[l] + cell),
                          __float_as_uint(obj_val));
            }
        }
    }

    // block reduction (block is single-level: l = blockIdx.x / 9)
    __shared__ float s0[256], s1[256], s2[256];
    const int t = threadIdx.x;
    s0[t] = box_c; s1[t] = cls_c; s2[t] = cnt_c;
    __syncthreads();
    for (int off = 128; off > 0; off >>= 1) {
        if (t < off) { s0[t] += s0[t+off]; s1[t] += s1[t+off]; s2[t] += s2[t+off]; }
        __syncthreads();
    }
    if (t == 0) {
        const int lv = blockIdx.x / 9;
        atomicAdd(&acc[0 + lv], s0[0]);   // box numerator
        atomicAdd(&acc[3 + lv], s1[0]);   // cls numerator
        atomicAdd(&acc[6 + lv], s2[0]);   // cnt
    }
}

// One thread per cell over all levels: 403200 = 1575 * 256 exactly.
// Per-level mean folded in as per-element weight -> single accumulator.
__global__ __launch_bounds__(256) void obj_kernel(
    const float* __restrict__ p0, const float* __restrict__ p1, const float* __restrict__ p2,
    const float* __restrict__ gt_obj, float* __restrict__ acc)
{
    const int idx = blockIdx.x * 256 + threadIdx.x;
    const float* p; int cell; float w;
    if (idx < CELLS0)                { p = p0; cell = idx;                    w = 1.f / (float)CELLS0; }
    else if (idx < CELLS0 + CELLS1)  { p = p1; cell = idx - CELLS0;          w = 1.f / (float)CELLS1; }
    else                             { p = p2; cell = idx - CELLS0 - CELLS1; w = 1.f / (float)CELLS2; }

    const float x = p[(long long)cell * NCH + 4];
    const float t = gt_obj[idx];
    float contrib = bce_logits(x, t) * w;

    __shared__ float red[256];
    red[threadIdx.x] = contrib;
    __syncthreads();
    for (int off = 128; off > 0; off >>= 1) {
        if (threadIdx.x < off) red[threadIdx.x] += red[threadIdx.x + off];
        __syncthreads();
    }
    if (threadIdx.x == 0) atomicAdd(&acc[9], red[0]);
}

__global__ void finalize_kernel(const float* __restrict__ acc, float* __restrict__ out)
{
    if (blockIdx.x == 0 && threadIdx.x == 0) {
        float lb = 0.f, lc = 0.f;
        for (int l = 0; l < 3; ++l) {
            const float cnt = fmaxf(acc[6 + l], 1.f);
            lb += acc[0 + l] / cnt;
            lc += acc[3 + l] / (cnt * (float)NCLS);
        }
        out[0] = 0.05f * lb;   // LOSS_W[0]
        out[1] = acc[9];       // LOSS_W[1] = 1.0
        out[2] = 0.5f  * lc;   // LOSS_W[2]
    }
}

extern "C" void kernel_launch(void* const* d_in, const int* in_sizes, int n_in,
                              void* d_out, int out_size, void* d_ws, size_t ws_size,
                              hipStream_t stream) {
    const float* p0       = (const float*)d_in[0];
    const float* p1       = (const float*)d_in[1];
    const float* p2       = (const float*)d_in[2];
    const float* gt_boxes = (const float*)d_in[3];
    const float* anchors  = (const float*)d_in[4];
    const int*   gt_labels= (const int*)d_in[5];
    const int*   image_ids= (const int*)d_in[6];
    float* out = (float*)d_out;

    float* ws     = (float*)d_ws;
    float* gt_obj = ws;                 // CELLS_TOTAL floats
    float* acc    = ws + CELLS_TOTAL;   // 16 floats: [0..2]=box, [3..5]=cls, [6..8]=cnt, [9]=obj

    // WS_FLOATS = 403216 floats = 100804 float4 exactly
    const int n4 = WS_FLOATS / 4;
    zero_ws_kernel<<<(n4 + 255) / 256, 256, 0, stream>>>((float4*)d_ws, n4);

    match_kernel<<<27, 256, 0, stream>>>(p0, p1, p2, gt_boxes, anchors,
                                         gt_labels, image_ids, gt_obj, acc);
    obj_kernel<<<1575, 256, 0, stream>>>(p0, p1, p2, gt_obj, acc);
    finalize_kernel<<<1, 64, 0, stream>>>(acc, out);
}